// Round 16
// baseline (419.030 us; speedup 1.0000x reference)
//
#include <hip/hip_runtime.h>
#include <math.h>

typedef float f32x4 __attribute__((ext_vector_type(4)));

// Problem constants (from reference setup_inputs)
constexpr int CAP = 262144;   // rows of keys/values
constexpr int NF  = 512;      // in_features == out_features

constexpr int G1  = 2048;     // blocks; 128 rows each (4 waves x 32 rows)
constexpr int RPB = CAP / G1; // 128 rows per block

// Sparsity cutoff: rows with logit < M - CUT are dropped from the NUMERATOR
// only (denominator S stays exact). Worst-case: dropped mass <=
// 262144*exp(-25)*max|v| ~ 2e-5 -> output shift <= 6e-6 << 1.9e-2 threshold.
// Deterministic predicate, identical in producer and consumers.
constexpr float CUT = 25.0f;

// ---------------------------------------------------------------------------
// k_logits helpers. NT loads PROVEN GOOD (R13 NT=117.3 vs R14 plain=129.0).
// ---------------------------------------------------------------------------
__device__ __forceinline__ void load8(const float* __restrict__ keys, int rb,
                                      int lane, f32x4* K0, f32x4* K1)
{
    #pragma unroll
    for (int i = 0; i < 8; ++i) {
        const float* kp = keys + (size_t)(rb + i) * NF + lane * 8;
        K0[i] = __builtin_nontemporal_load(reinterpret_cast<const f32x4*>(kp));
        K1[i] = __builtin_nontemporal_load(reinterpret_cast<const f32x4*>(kp + 4));
    }
}

__device__ __forceinline__ float dist2(const f32x4 k0, const f32x4 k1,
                                       const f32x4 q0, const f32x4 q1)
{
    return fabsf(k0[0] - q0[0]) + fabsf(k0[1] - q0[1])
         + fabsf(k0[2] - q0[2]) + fabsf(k0[3] - q0[3])
         + fabsf(k1[0] - q1[0]) + fabsf(k1[1] - q1[1])
         + fabsf(k1[2] - q1[2]) + fabsf(k1[3] - q1[3]);
}

// ---------------------------------------------------------------------------
// Kernel 1 (keys, 512MB stream): EXACT R13 hot loop (8-row batches, 10-shfl
// batched butterfly, register prefetch). NEW: last-block tail (threadfence +
// atomic counter, CUDA threadFenceReduction pattern) computes global M,
// invS, and the ascending valid-block list + weights exp(pm[b]-M) — the
// work previously done redundantly in k_wsum/k_red/k_final block scans.
// Output-deterministic: the tail is a pure fixed-order function of pm/ps,
// regardless of WHICH block executes it.
// ---------------------------------------------------------------------------
__global__ __launch_bounds__(256) void k_logits(
    const float* __restrict__ q, const float* __restrict__ keys,
    float* __restrict__ logits, float* __restrict__ pm, float* __restrict__ ps,
    float* __restrict__ scal, float* __restrict__ vw, int* __restrict__ vidx,
    unsigned* __restrict__ counter)
{
    const int tid  = threadIdx.x;
    const int lane = tid & 63;
    const int wv   = tid >> 6;
    const int w    = blockIdx.x * 4 + wv;
    const int row0 = w * 32;

    const f32x4 q0 = *reinterpret_cast<const f32x4*>(q + lane * 8);
    const f32x4 q1 = *reinterpret_cast<const f32x4*>(q + lane * 8 + 4);

    float m = -INFINITY, s = 0.f;   // per-lane online softmax state

    f32x4 K0[8], K1[8];
    load8(keys, row0, lane, K0, K1);

    #pragma unroll
    for (int b = 0; b < 4; ++b) {
        const int rb = row0 + b * 8;

        float d[8];
        #pragma unroll
        for (int i = 0; i < 8; ++i) d[i] = dist2(K0[i], K1[i], q0, q1);

        if (b < 3) load8(keys, rb + 8, lane, K0, K1);   // prefetch next batch

        // batched reduction: 8 rows in 10 shfls (lane l ends with row l&7)
        float p[4];
        #pragma unroll
        for (int i = 0; i < 4; ++i) {
            const float x = d[2 * i], y = d[2 * i + 1];
            const float keep = (lane & 1) ? y : x;
            const float send = (lane & 1) ? x : y;
            p[i] = keep + __shfl_xor(send, 1, 64);
        }
        float e[2];
        #pragma unroll
        for (int i = 0; i < 2; ++i) {
            const float x = p[2 * i], y = p[2 * i + 1];
            const float keep = (lane & 2) ? y : x;
            const float send = (lane & 2) ? x : y;
            e[i] = keep + __shfl_xor(send, 2, 64);
        }
        {
            const float keep = (lane & 4) ? e[1] : e[0];
            const float send = (lane & 4) ? e[0] : e[1];
            e[0] = keep + __shfl_xor(send, 4, 64);
        }
        float r = e[0];
        r += __shfl_xor(r, 8, 64);
        r += __shfl_xor(r, 16, 64);
        r += __shfl_xor(r, 32, 64);

        const float L = -r;                 // logit of row rb + (lane & 7)
        if (lane < 8) logits[rb + lane] = L;

        const float Mn = fmaxf(m, L);
        s = s * __expf(m - Mn) + __expf(L - Mn);   // exp(-inf)=0 handles init
        m = Mn;
    }

    // rows replicated in 8 lane-groups (bit-identical) -> exact 1/8 scale
    s *= 0.125f;
    #pragma unroll
    for (int off = 1; off < 64; off <<= 1) {
        const float m2 = __shfl_xor(m, off, 64);
        const float s2 = __shfl_xor(s, off, 64);
        const float Mn = fmaxf(m, m2);
        s = s * __expf(m - Mn) + s2 * __expf(m2 - Mn);
        m = Mn;
    }

    __shared__ float sm[4], ss[4];
    __shared__ int amLast;
    if (lane == 0) { sm[wv] = m; ss[wv] = s; }
    __syncthreads();
    if (tid == 0) {
        float M = sm[0], S = ss[0];
        #pragma unroll
        for (int i = 1; i < 4; ++i) {
            const float Mn = fmaxf(M, sm[i]);
            S = S * __expf(M - Mn) + ss[i] * __expf(sm[i] - Mn);
            M = Mn;
        }
        pm[blockIdx.x] = M;
        ps[blockIdx.x] = S;
        __threadfence();                         // publish pm/ps device-wide
        const unsigned old = atomicAdd(counter, 1u);
        amLast = (old == G1 - 1);
    }
    __syncthreads();
    if (!amLast) return;
    __threadfence();                             // acquire all blocks' pm/ps

    // ---- last-block tail: M, S, valid list (fixed order, deterministic) ----
    float mx = -INFINITY;
    for (int i = tid; i < G1; i += 256) mx = fmaxf(mx, pm[i]);
    #pragma unroll
    for (int off = 1; off < 64; off <<= 1) mx = fmaxf(mx, __shfl_xor(mx, off, 64));
    if (lane == 0) sm[wv] = mx;
    __syncthreads();
    const float M = fmaxf(fmaxf(sm[0], sm[1]), fmaxf(sm[2], sm[3]));

    float sacc = 0.f;
    for (int i = tid; i < G1; i += 256) sacc += ps[i] * __expf(pm[i] - M);
    #pragma unroll
    for (int off = 1; off < 64; off <<= 1) sacc += __shfl_xor(sacc, off, 64);
    if (lane == 0) ss[wv] = sacc;
    __syncthreads();
    if (tid == 0) {
        scal[0] = M;
        scal[1] = 1.f / (ss[0] + ss[1] + ss[2] + ss[3]);
    }

    // valid-block list, ascending (contiguous 8-chunks + LDS prefix sum)
    __shared__ int cnt[256];
    int loc[8], c = 0;
    const int base = tid * 8;                    // 256*8 = 2048 = G1
    #pragma unroll
    for (int j = 0; j < 8; ++j)
        if (pm[base + j] >= M - CUT) loc[c++] = base + j;
    cnt[tid] = c;
    __syncthreads();
    if (tid == 0) {
        int run = 0;
        for (int i = 0; i < 256; ++i) { const int t = cnt[i]; cnt[i] = run; run += t; }
        vidx[G1] = run;                          // count stored past the list
    }
    __syncthreads();
    const int off0 = cnt[tid];
    for (int j = 0; j < c; ++j) {
        vidx[off0 + j] = loc[j];
        vw[off0 + j]   = __expf(pm[loc[j]] - M);
    }
}

// ---------------------------------------------------------------------------
// Kernel 2 (SPARSE value pass + in-kernel final reduce): block b exits the
// accumulation unless pm[b] >= M - CUT (M read from scal — no scan).
// ALL blocks join the completion counter; the last block gathers the valid
// partial rows via the precomputed list (R12 lesson: the gather is ~nv*2
// independent loads per thread, nv ~ tens — latency-pipelined, not serial)
// and writes sigmoid(acc * invS).
// ---------------------------------------------------------------------------
__global__ __launch_bounds__(256) void k_wsum_sparse(
    const float* __restrict__ vals, const float* __restrict__ logits,
    const float* __restrict__ pm, const float* __restrict__ scal,
    const float* __restrict__ vw, const int* __restrict__ vidx,
    float* __restrict__ partial, unsigned* __restrict__ counter,
    float* __restrict__ out)
{
    const int tid = threadIdx.x;
    const float M    = scal[0];
    const float invS = scal[1];
    const float mb   = pm[blockIdx.x];
    __shared__ int amLast;

    if (mb >= M - CUT) {                      // block-uniform: do the work
        const int col = (tid & 127) * 4;
        const int rg  = tid >> 7;
        const size_t gr0 = (size_t)blockIdx.x * RPB;

        f32x4 acc = {0.f, 0.f, 0.f, 0.f};
        for (int r = rg; r < RPB; r += 2) {
            const float L = logits[gr0 + r];  // same addr across subgroup
            if (L < M - CUT) continue;        // subgroup-uniform skip
            const float w = __expf(L - mb);
            const f32x4 v = *reinterpret_cast<const f32x4*>(vals + (gr0 + r) * NF + col);
            acc += w * v;
        }

        __shared__ float sp[NF];
        if (rg == 0) *reinterpret_cast<f32x4*>(sp + col) = acc;
        __syncthreads();
        if (rg == 1) {
            sp[col + 0] += acc[0]; sp[col + 1] += acc[1];
            sp[col + 2] += acc[2]; sp[col + 3] += acc[3];
        }
        __syncthreads();
        if (rg == 0)
            *reinterpret_cast<f32x4*>(partial + (size_t)blockIdx.x * NF + col) =
                *reinterpret_cast<const f32x4*>(sp + col);
    }

    __threadfence();                          // publish partial (if written)
    __syncthreads();
    if (tid == 0) {
        const unsigned old = atomicAdd(counter, 1u);
        amLast = (old == G1 - 1);
    }
    __syncthreads();
    if (!amLast) return;
    __threadfence();                          // acquire all partial rows

    // ---- final gather: 256 threads x 2 cols, valid list (ascending) ----
    const int nv = vidx[G1];
    float a0 = 0.f, a1 = 0.f;
    for (int i = 0; i < nv; ++i) {
        const int   r = vidx[i];
        const float w = vw[i];
        a0 += w * partial[(size_t)r * NF + tid];
        a1 += w * partial[(size_t)r * NF + tid + 256];
    }
    out[tid]       = 1.f / (1.f + __expf(-a0 * invS));
    out[tid + 256] = 1.f / (1.f + __expf(-a1 * invS));
}

// ---------------------------------------------------------------------------
extern "C" void kernel_launch(void* const* d_in, const int* in_sizes, int n_in,
                              void* d_out, int out_size, void* d_ws, size_t ws_size,
                              hipStream_t stream)
{
    const float* q    = (const float*)d_in[0];   // [512]
    const float* keys = (const float*)d_in[1];   // [262144, 512]
    const float* vals = (const float*)d_in[2];   // [262144, 512]
    float* out = (float*)d_out;                  // [512]

    // Workspace layout (floats unless noted). Total ~5.3 MB.
    float* ws      = (float*)d_ws;
    float* logits  = ws;                         // CAP (1 MB)
    float* pm      = logits + CAP;               // G1
    float* ps      = pm + G1;                    // G1
    float* scal    = ps + G1;                    // 4
    float* vw      = scal + 4;                   // G1
    float* partial = vw + G1;                    // G1*NF (4 MB)
    int*   vidx    = (int*)(partial + (size_t)G1 * NF);  // G1+4 ints
    unsigned* ctrs = (unsigned*)(vidx + G1 + 4); // 2 counters (16B-aligned)

    // reset completion counters (graph-legal memset node, stream-ordered)
    hipMemsetAsync(ctrs, 0, 2 * sizeof(unsigned), stream);

    k_logits     <<<G1, 256, 0, stream>>>(q, keys, logits, pm, ps,
                                          scal, vw, vidx, ctrs + 0);
    k_wsum_sparse<<<G1, 256, 0, stream>>>(vals, logits, pm, scal, vw, vidx,
                                          partial, ctrs + 1, out);
}

// Round 17
// 118.892 us; speedup vs baseline: 3.5245x; 3.5245x over previous
//
#include <hip/hip_runtime.h>
#include <math.h>

typedef float f32x4 __attribute__((ext_vector_type(4)));

// Problem constants (from reference setup_inputs)
constexpr int CAP = 262144;   // rows of keys/values
constexpr int NF  = 512;      // in_features == out_features

constexpr int G1  = 2048;     // blocks; 128 rows each (4 waves x 32 rows)
constexpr int RPB = CAP / G1; // 128 rows per block
constexpr int GR  = 64;       // k_red blocks
constexpr int RPR = G1 / GR;  // 32 partial rows per red block

// Sparsity cutoff: rows with logit < M - CUT are dropped from the NUMERATOR
// only (denominator S stays exact). Worst-case: dropped mass <=
// 262144*exp(-25)*max|v| ~ 2e-5 -> output shift <= 6e-6 << 1.9e-2 threshold.
// Deterministic predicate, identical in producer and consumers.
constexpr float CUT = 25.0f;

// ---------------------------------------------------------------------------
// helpers for k_logits: load 8 rows (2 f32x4/lane each), L1-distance vs q.
// NT loads PROVEN GOOD (R13 NT=117.3 vs R14 plain=129.0): L2-bypass keeps
// the 512MB dead stream out of the cache.
// ---------------------------------------------------------------------------
__device__ __forceinline__ void load8(const float* __restrict__ keys, int rb,
                                      int lane, f32x4* K0, f32x4* K1)
{
    #pragma unroll
    for (int i = 0; i < 8; ++i) {
        const float* kp = keys + (size_t)(rb + i) * NF + lane * 8;
        K0[i] = __builtin_nontemporal_load(reinterpret_cast<const f32x4*>(kp));
        K1[i] = __builtin_nontemporal_load(reinterpret_cast<const f32x4*>(kp + 4));
    }
}

__device__ __forceinline__ float dist2(const f32x4 k0, const f32x4 k1,
                                       const f32x4 q0, const f32x4 q1)
{
    return fabsf(k0[0] - q0[0]) + fabsf(k0[1] - q0[1])
         + fabsf(k0[2] - q0[2]) + fabsf(k0[3] - q0[3])
         + fabsf(k1[0] - q1[0]) + fabsf(k1[1] - q1[1])
         + fabsf(k1[2] - q1[2]) + fabsf(k1[3] - q1[3]);
}

// ---------------------------------------------------------------------------
// Kernel 1 (keys, 512MB stream) — proven R10/R13 version (117.3 us total).
// 8-row batches, 10-shfl batched butterfly, register prefetch of batch b+1
// issued before batch b's serial shfl/exp tail.
// Settled micro-experiments: NO min-waves launch_bounds (R11: VGPR cap 64 ->
// spills, 2x); NO plain loads (R14: -12 us); ping-pong dbuf = null (R15);
// NO cross-block fence fusion (R16: device-scope fences on non-coherent
// XCD L2s -> 3.5x).
// ---------------------------------------------------------------------------
__global__ __launch_bounds__(256) void k_logits(
    const float* __restrict__ q, const float* __restrict__ keys,
    float* __restrict__ logits, float* __restrict__ pm, float* __restrict__ ps)
{
    const int tid  = threadIdx.x;
    const int lane = tid & 63;
    const int wv   = tid >> 6;
    const int w    = blockIdx.x * 4 + wv;
    const int row0 = w * 32;

    const f32x4 q0 = *reinterpret_cast<const f32x4*>(q + lane * 8);
    const f32x4 q1 = *reinterpret_cast<const f32x4*>(q + lane * 8 + 4);

    float m = -INFINITY, s = 0.f;   // per-lane online softmax state

    f32x4 K0[8], K1[8];
    load8(keys, row0, lane, K0, K1);

    #pragma unroll
    for (int b = 0; b < 4; ++b) {
        const int rb = row0 + b * 8;

        // consume current batch -> per-lane partial distances
        float d[8];
        #pragma unroll
        for (int i = 0; i < 8; ++i) d[i] = dist2(K0[i], K1[i], q0, q1);

        // prefetch next batch (issued before the serial butterfly tail)
        if (b < 3) load8(keys, rb + 8, lane, K0, K1);

        // batched reduction: 8 rows in 10 shfls (lane l ends with row l&7)
        float p[4];
        #pragma unroll
        for (int i = 0; i < 4; ++i) {
            const float x = d[2 * i], y = d[2 * i + 1];
            const float keep = (lane & 1) ? y : x;
            const float send = (lane & 1) ? x : y;
            p[i] = keep + __shfl_xor(send, 1, 64);
        }
        float e[2];
        #pragma unroll
        for (int i = 0; i < 2; ++i) {
            const float x = p[2 * i], y = p[2 * i + 1];
            const float keep = (lane & 2) ? y : x;
            const float send = (lane & 2) ? x : y;
            e[i] = keep + __shfl_xor(send, 2, 64);
        }
        {
            const float keep = (lane & 4) ? e[1] : e[0];
            const float send = (lane & 4) ? e[0] : e[1];
            e[0] = keep + __shfl_xor(send, 4, 64);
        }
        float r = e[0];
        r += __shfl_xor(r, 8, 64);
        r += __shfl_xor(r, 16, 64);
        r += __shfl_xor(r, 32, 64);

        const float L = -r;                 // logit of row rb + (lane & 7)
        if (lane < 8) logits[rb + lane] = L;

        const float Mn = fmaxf(m, L);
        s = s * __expf(m - Mn) + __expf(L - Mn);   // exp(-inf)=0 handles init
        m = Mn;
    }

    // rows replicated in 8 lane-groups (bit-identical) -> exact 1/8 scale
    s *= 0.125f;
    #pragma unroll
    for (int off = 1; off < 64; off <<= 1) {
        const float m2 = __shfl_xor(m, off, 64);
        const float s2 = __shfl_xor(s, off, 64);
        const float Mn = fmaxf(m, m2);
        s = s * __expf(m - Mn) + s2 * __expf(m2 - Mn);
        m = Mn;
    }

    __shared__ float sm[4], ss[4];
    if (lane == 0) { sm[wv] = m; ss[wv] = s; }
    __syncthreads();
    if (tid == 0) {
        float M = sm[0], S = ss[0];
        #pragma unroll
        for (int i = 1; i < 4; ++i) {
            const float Mn = fmaxf(M, sm[i]);
            S = S * __expf(M - Mn) + ss[i] * __expf(sm[i] - Mn);
            M = Mn;
        }
        pm[blockIdx.x] = M;
        ps[blockIdx.x] = S;
    }
}

// ---------------------------------------------------------------------------
// inline global-max helper: exact fmax scan of pm[G1] (8KB, L2-resident).
// Order-independent -> bit-identical in every block of every kernel.
// Uses one __syncthreads; call before any divergent exit.
// ---------------------------------------------------------------------------
__device__ __forceinline__ float global_max(const float* __restrict__ pm,
                                            int tid, int lane, int wv)
{
    float mx = -INFINITY;
    for (int i = tid; i < G1; i += 256) mx = fmaxf(mx, pm[i]);
    #pragma unroll
    for (int off = 1; off < 64; off <<= 1) mx = fmaxf(mx, __shfl_xor(mx, off, 64));
    __shared__ float smx[4];
    if (lane == 0) smx[wv] = mx;
    __syncthreads();
    return fmaxf(fmaxf(smx[0], smx[1]), fmaxf(smx[2], smx[3]));
}

// ---------------------------------------------------------------------------
// Kernel 2 (SPARSE value pass): M computed inline. Block b exits unless
// pm[b] >= M - CUT; surviving blocks stream only rows with logit >= M - CUT.
// partial[b] = sum_kept exp(L - pm[b]) * v_row. Unwritten partial rows are
// never read (k_red uses the same predicate).
// ---------------------------------------------------------------------------
__global__ __launch_bounds__(256) void k_wsum_sparse(
    const float* __restrict__ vals, const float* __restrict__ logits,
    const float* __restrict__ pm, float* __restrict__ partial)
{
    const int tid  = threadIdx.x;
    const int lane = tid & 63;
    const int wv   = tid >> 6;

    const float M  = global_max(pm, tid, lane, wv);   // contains __syncthreads
    const float mb = pm[blockIdx.x];
    if (mb < M - CUT) return;                 // block-uniform early exit

    const int col = (tid & 127) * 4;
    const int rg  = tid >> 7;
    const size_t gr0 = (size_t)blockIdx.x * RPB;

    f32x4 acc = {0.f, 0.f, 0.f, 0.f};
    for (int r = rg; r < RPB; r += 2) {
        const float L = logits[gr0 + r];      // same addr across subgroup
        if (L < M - CUT) continue;            // subgroup-uniform skip
        const float w = __expf(L - mb);
        const f32x4 v = *reinterpret_cast<const f32x4*>(vals + (gr0 + r) * NF + col);
        acc += w * v;
    }

    __shared__ float sp[NF];
    if (rg == 0) *reinterpret_cast<f32x4*>(sp + col) = acc;
    __syncthreads();
    if (rg == 1) {
        sp[col + 0] += acc[0]; sp[col + 1] += acc[1];
        sp[col + 2] += acc[2]; sp[col + 3] += acc[3];
    }
    __syncthreads();
    if (rg == 0)
        *reinterpret_cast<f32x4*>(partial + (size_t)blockIdx.x * NF + col) =
            *reinterpret_cast<const f32x4*>(sp + col);
}

// ---------------------------------------------------------------------------
// Kernel 3: reduce valid partial rows -> GR rows, scaled by exp(pm[r] - M).
// 64 BLOCKS IN PARALLEL (R12 lesson: folding this scan into the 2-block
// k_final serializes ~512 latency-bound loads on 2 CUs -> +115 us).
// ---------------------------------------------------------------------------
__global__ __launch_bounds__(256) void k_red(
    const float* __restrict__ pm, const float* __restrict__ partial,
    float* __restrict__ part2)
{
    const int tid  = threadIdx.x;
    const int lane = tid & 63;
    const int wv   = tid >> 6;

    const float M = global_max(pm, tid, lane, wv);

    const int col = (tid & 127) * 4;
    const int rg  = tid >> 7;
    const int r0  = blockIdx.x * RPR;

    f32x4 acc = {0.f, 0.f, 0.f, 0.f};
    for (int r = r0 + rg; r < r0 + RPR; r += 2) {
        const float mbr = pm[r];
        if (mbr < M - CUT) continue;          // skip never-written rows
        const float sc = __expf(mbr - M);
        const f32x4 v = *reinterpret_cast<const f32x4*>(partial + (size_t)r * NF + col);
        acc += sc * v;
    }

    __shared__ float sp[NF];
    if (rg == 0) *reinterpret_cast<f32x4*>(sp + col) = acc;
    __syncthreads();
    if (rg == 1) {
        sp[col + 0] += acc[0]; sp[col + 1] += acc[1];
        sp[col + 2] += acc[2]; sp[col + 3] += acc[3];
    }
    __syncthreads();
    if (rg == 0)
        *reinterpret_cast<f32x4*>(part2 + (size_t)blockIdx.x * NF + col) =
            *reinterpret_cast<const f32x4*>(sp + col);
}

// ---------------------------------------------------------------------------
// Kernel 4: final. M and S = sum_b s_b*exp(m_b-M) inline (deterministic,
// identical in both blocks); DENSE sum of the GR part2 rows; normalize;
// sigmoid.
// ---------------------------------------------------------------------------
__global__ __launch_bounds__(256) void k_final(
    const float* __restrict__ pm, const float* __restrict__ ps,
    const float* __restrict__ part2, float* __restrict__ out)
{
    const int tid  = threadIdx.x;
    const int lane = tid & 63;
    const int wv   = tid >> 6;

    const float M = global_max(pm, tid, lane, wv);

    float sacc = 0.f;
    for (int i = tid; i < G1; i += 256) sacc += ps[i] * __expf(pm[i] - M);
    #pragma unroll
    for (int off = 1; off < 64; off <<= 1) sacc += __shfl_xor(sacc, off, 64);
    __shared__ float ss[4];
    if (lane == 0) ss[wv] = sacc;
    __syncthreads();
    const float invS = 1.f / (ss[0] + ss[1] + ss[2] + ss[3]);

    const int o = blockIdx.x * 256 + tid;          // grid 2 x 256 = 512
    float acc = 0.f;
    #pragma unroll 8
    for (int j = 0; j < GR; ++j) acc += part2[(size_t)j * NF + o];
    out[o] = 1.f / (1.f + __expf(-acc * invS));
}

// ---------------------------------------------------------------------------
extern "C" void kernel_launch(void* const* d_in, const int* in_sizes, int n_in,
                              void* d_out, int out_size, void* d_ws, size_t ws_size,
                              hipStream_t stream)
{
    const float* q    = (const float*)d_in[0];   // [512]
    const float* keys = (const float*)d_in[1];   // [262144, 512]
    const float* vals = (const float*)d_in[2];   // [262144, 512]
    float* out = (float*)d_out;                  // [512]

    // Workspace layout (floats). Total ~5.4 MB.
    float* ws      = (float*)d_ws;
    float* logits  = ws;                         // CAP (1 MB)
    float* pm      = logits + CAP;               // G1 (16B-aligned)
    float* ps      = pm + G1;                    // G1
    float* partial = ps + G1;                    // G1*NF (4 MB)
    float* part2   = partial + (size_t)G1 * NF;  // GR*NF (128 KB)

    k_logits     <<<G1, 256, 0, stream>>>(q, keys, logits, pm, ps);
    k_wsum_sparse<<<G1, 256, 0, stream>>>(vals, logits, pm, partial);
    k_red        <<<GR, 256, 0, stream>>>(pm, partial, part2);
    k_final      <<<2,  256, 0, stream>>>(pm, ps, part2, out);
}

// Round 18
// 111.095 us; speedup vs baseline: 3.7718x; 1.0702x over previous
//
#include <hip/hip_runtime.h>
#include <math.h>

typedef float f32x4 __attribute__((ext_vector_type(4)));

// Problem constants (from reference setup_inputs)
constexpr int CAP = 262144;   // rows of keys/values
constexpr int NF  = 512;      // in_features == out_features

constexpr int G1  = 2048;     // blocks; 128 rows each (4 waves x 32 rows)
constexpr int RPB = CAP / G1; // 128 rows per block
constexpr int GR  = 64;       // k_red blocks
constexpr int RPR = G1 / GR;  // 32 partial rows per red block

// Sparsity cutoff: rows with logit < M - CUT are dropped from the NUMERATOR
// only (denominator S stays exact). Worst-case: dropped mass <=
// 262144*exp(-25)*max|v| ~ 2e-5 -> output shift <= 6e-6 << 1.9e-2 threshold.
// Deterministic predicate, identical in producer and consumers.
constexpr float CUT = 25.0f;

// ---------------------------------------------------------------------------
// k_logits helpers — R18 layout change: DENSE-PER-INSTRUCTION loads.
// Old: lane*8 / lane*8+4 -> each dwordx4 instruction touches 16B at stride
// 32B (half of every 64B line); with NT (L2-bypass) each line is fetched
// TWICE from HBM -> ~2x read traffic. New (R8-proven): lane*4 and
// 256+lane*4 -> each instruction covers one contiguous 1KB segment.
// NT itself is PROVEN GOOD (R13 vs R14: +12 us).
// ---------------------------------------------------------------------------
__device__ __forceinline__ void load8(const float* __restrict__ keys, int rb,
                                      int lane, f32x4* K0, f32x4* K1)
{
    #pragma unroll
    for (int i = 0; i < 8; ++i) {
        const float* kp = keys + (size_t)(rb + i) * NF + lane * 4;
        K0[i] = __builtin_nontemporal_load(reinterpret_cast<const f32x4*>(kp));
        K1[i] = __builtin_nontemporal_load(reinterpret_cast<const f32x4*>(kp + 256));
    }
}

__device__ __forceinline__ float dist2(const f32x4 k0, const f32x4 k1,
                                       const f32x4 q0, const f32x4 q1)
{
    return fabsf(k0[0] - q0[0]) + fabsf(k0[1] - q0[1])
         + fabsf(k0[2] - q0[2]) + fabsf(k0[3] - q0[3])
         + fabsf(k1[0] - q1[0]) + fabsf(k1[1] - q1[1])
         + fabsf(k1[2] - q1[2]) + fabsf(k1[3] - q1[3]);
}

// ---------------------------------------------------------------------------
// Kernel 1 (keys, 512MB stream) — R13 structure (8-row batches, 10-shfl
// batched butterfly, register prefetch), R18 dense load layout.
// Settled: NO min-waves launch_bounds (R11: spills, 2x); NT > plain (R14);
// ping-pong dbuf null (R15); NO cross-block fences (R16: 3.5x).
// ---------------------------------------------------------------------------
__global__ __launch_bounds__(256) void k_logits(
    const float* __restrict__ q, const float* __restrict__ keys,
    float* __restrict__ logits, float* __restrict__ pm, float* __restrict__ ps)
{
    const int tid  = threadIdx.x;
    const int lane = tid & 63;
    const int wv   = tid >> 6;
    const int w    = blockIdx.x * 4 + wv;
    const int row0 = w * 32;

    const f32x4 q0 = *reinterpret_cast<const f32x4*>(q + lane * 4);
    const f32x4 q1 = *reinterpret_cast<const f32x4*>(q + lane * 4 + 256);

    float m = -INFINITY, s = 0.f;   // per-lane online softmax state

    f32x4 K0[8], K1[8];
    load8(keys, row0, lane, K0, K1);

    #pragma unroll
    for (int b = 0; b < 4; ++b) {
        const int rb = row0 + b * 8;

        // consume current batch -> per-lane partial distances
        float d[8];
        #pragma unroll
        for (int i = 0; i < 8; ++i) d[i] = dist2(K0[i], K1[i], q0, q1);

        // prefetch next batch (issued before the serial butterfly tail)
        if (b < 3) load8(keys, rb + 8, lane, K0, K1);

        // batched reduction: 8 rows in 10 shfls (lane l ends with row l&7)
        float p[4];
        #pragma unroll
        for (int i = 0; i < 4; ++i) {
            const float x = d[2 * i], y = d[2 * i + 1];
            const float keep = (lane & 1) ? y : x;
            const float send = (lane & 1) ? x : y;
            p[i] = keep + __shfl_xor(send, 1, 64);
        }
        float e[2];
        #pragma unroll
        for (int i = 0; i < 2; ++i) {
            const float x = p[2 * i], y = p[2 * i + 1];
            const float keep = (lane & 2) ? y : x;
            const float send = (lane & 2) ? x : y;
            e[i] = keep + __shfl_xor(send, 2, 64);
        }
        {
            const float keep = (lane & 4) ? e[1] : e[0];
            const float send = (lane & 4) ? e[0] : e[1];
            e[0] = keep + __shfl_xor(send, 4, 64);
        }
        float r = e[0];
        r += __shfl_xor(r, 8, 64);
        r += __shfl_xor(r, 16, 64);
        r += __shfl_xor(r, 32, 64);

        const float L = -r;                 // logit of row rb + (lane & 7)
        if (lane < 8) logits[rb + lane] = L;

        const float Mn = fmaxf(m, L);
        s = s * __expf(m - Mn) + __expf(L - Mn);   // exp(-inf)=0 handles init
        m = Mn;
    }

    // rows replicated in 8 lane-groups (bit-identical) -> exact 1/8 scale
    s *= 0.125f;
    #pragma unroll
    for (int off = 1; off < 64; off <<= 1) {
        const float m2 = __shfl_xor(m, off, 64);
        const float s2 = __shfl_xor(s, off, 64);
        const float Mn = fmaxf(m, m2);
        s = s * __expf(m - Mn) + s2 * __expf(m2 - Mn);
        m = Mn;
    }

    __shared__ float sm[4], ss[4];
    if (lane == 0) { sm[wv] = m; ss[wv] = s; }
    __syncthreads();
    if (tid == 0) {
        float M = sm[0], S = ss[0];
        #pragma unroll
        for (int i = 1; i < 4; ++i) {
            const float Mn = fmaxf(M, sm[i]);
            S = S * __expf(M - Mn) + ss[i] * __expf(sm[i] - Mn);
            M = Mn;
        }
        pm[blockIdx.x] = M;
        ps[blockIdx.x] = S;
    }
}

// ---------------------------------------------------------------------------
// inline global-max helper: exact fmax scan of pm[G1] (8KB, L2-resident).
// Order-independent -> bit-identical in every block of every kernel.
// Uses one __syncthreads; call before any divergent exit.
// ---------------------------------------------------------------------------
__device__ __forceinline__ float global_max(const float* __restrict__ pm,
                                            int tid, int lane, int wv)
{
    float mx = -INFINITY;
    for (int i = tid; i < G1; i += 256) mx = fmaxf(mx, pm[i]);
    #pragma unroll
    for (int off = 1; off < 64; off <<= 1) mx = fmaxf(mx, __shfl_xor(mx, off, 64));
    __shared__ float smx[4];
    if (lane == 0) smx[wv] = mx;
    __syncthreads();
    return fmaxf(fmaxf(smx[0], smx[1]), fmaxf(smx[2], smx[3]));
}

// ---------------------------------------------------------------------------
// Kernel 2 (SPARSE value pass): M computed inline. Block b exits unless
// pm[b] >= M - CUT; surviving blocks stream only rows with logit >= M - CUT.
// partial[b] = sum_kept exp(L - pm[b]) * v_row. Unwritten partial rows are
// never read (k_red uses the same predicate).
// ---------------------------------------------------------------------------
__global__ __launch_bounds__(256) void k_wsum_sparse(
    const float* __restrict__ vals, const float* __restrict__ logits,
    const float* __restrict__ pm, float* __restrict__ partial)
{
    const int tid  = threadIdx.x;
    const int lane = tid & 63;
    const int wv   = tid >> 6;

    const float M  = global_max(pm, tid, lane, wv);   // contains __syncthreads
    const float mb = pm[blockIdx.x];
    if (mb < M - CUT) return;                 // block-uniform early exit

    const int col = (tid & 127) * 4;
    const int rg  = tid >> 7;
    const size_t gr0 = (size_t)blockIdx.x * RPB;

    f32x4 acc = {0.f, 0.f, 0.f, 0.f};
    for (int r = rg; r < RPB; r += 2) {
        const float L = logits[gr0 + r];      // same addr across subgroup
        if (L < M - CUT) continue;            // subgroup-uniform skip
        const float w = __expf(L - mb);
        const f32x4 v = *reinterpret_cast<const f32x4*>(vals + (gr0 + r) * NF + col);
        acc += w * v;
    }

    __shared__ float sp[NF];
    if (rg == 0) *reinterpret_cast<f32x4*>(sp + col) = acc;
    __syncthreads();
    if (rg == 1) {
        sp[col + 0] += acc[0]; sp[col + 1] += acc[1];
        sp[col + 2] += acc[2]; sp[col + 3] += acc[3];
    }
    __syncthreads();
    if (rg == 0)
        *reinterpret_cast<f32x4*>(partial + (size_t)blockIdx.x * NF + col) =
            *reinterpret_cast<const f32x4*>(sp + col);
}

// ---------------------------------------------------------------------------
// Kernel 3: reduce valid partial rows -> GR rows, scaled by exp(pm[r] - M).
// 64 BLOCKS IN PARALLEL (R12 lesson: folding this scan into the 2-block
// k_final serializes ~512 latency-bound loads on 2 CUs -> +115 us).
// ---------------------------------------------------------------------------
__global__ __launch_bounds__(256) void k_red(
    const float* __restrict__ pm, const float* __restrict__ partial,
    float* __restrict__ part2)
{
    const int tid  = threadIdx.x;
    const int lane = tid & 63;
    const int wv   = tid >> 6;

    const float M = global_max(pm, tid, lane, wv);

    const int col = (tid & 127) * 4;
    const int rg  = tid >> 7;
    const int r0  = blockIdx.x * RPR;

    f32x4 acc = {0.f, 0.f, 0.f, 0.f};
    for (int r = r0 + rg; r < r0 + RPR; r += 2) {
        const float mbr = pm[r];
        if (mbr < M - CUT) continue;          // skip never-written rows
        const float sc = __expf(mbr - M);
        const f32x4 v = *reinterpret_cast<const f32x4*>(partial + (size_t)r * NF + col);
        acc += sc * v;
    }

    __shared__ float sp[NF];
    if (rg == 0) *reinterpret_cast<f32x4*>(sp + col) = acc;
    __syncthreads();
    if (rg == 1) {
        sp[col + 0] += acc[0]; sp[col + 1] += acc[1];
        sp[col + 2] += acc[2]; sp[col + 3] += acc[3];
    }
    __syncthreads();
    if (rg == 0)
        *reinterpret_cast<f32x4*>(part2 + (size_t)blockIdx.x * NF + col) =
            *reinterpret_cast<const f32x4*>(sp + col);
}

// ---------------------------------------------------------------------------
// Kernel 4: final. M and S = sum_b s_b*exp(m_b-M) inline (deterministic,
// identical in both blocks); DENSE sum of the GR part2 rows; normalize;
// sigmoid.
// ---------------------------------------------------------------------------
__global__ __launch_bounds__(256) void k_final(
    const float* __restrict__ pm, const float* __restrict__ ps,
    const float* __restrict__ part2, float* __restrict__ out)
{
    const int tid  = threadIdx.x;
    const int lane = tid & 63;
    const int wv   = tid >> 6;

    const float M = global_max(pm, tid, lane, wv);

    float sacc = 0.f;
    for (int i = tid; i < G1; i += 256) sacc += ps[i] * __expf(pm[i] - M);
    #pragma unroll
    for (int off = 1; off < 64; off <<= 1) sacc += __shfl_xor(sacc, off, 64);
    __shared__ float ss[4];
    if (lane == 0) ss[wv] = sacc;
    __syncthreads();
    const float invS = 1.f / (ss[0] + ss[1] + ss[2] + ss[3]);

    const int o = blockIdx.x * 256 + tid;          // grid 2 x 256 = 512
    float acc = 0.f;
    #pragma unroll 8
    for (int j = 0; j < GR; ++j) acc += part2[(size_t)j * NF + o];
    out[o] = 1.f / (1.f + __expf(-acc * invS));
}

// ---------------------------------------------------------------------------
extern "C" void kernel_launch(void* const* d_in, const int* in_sizes, int n_in,
                              void* d_out, int out_size, void* d_ws, size_t ws_size,
                              hipStream_t stream)
{
    const float* q    = (const float*)d_in[0];   // [512]
    const float* keys = (const float*)d_in[1];   // [262144, 512]
    const float* vals = (const float*)d_in[2];   // [262144, 512]
    float* out = (float*)d_out;                  // [512]

    // Workspace layout (floats). Total ~5.4 MB.
    float* ws      = (float*)d_ws;
    float* logits  = ws;                         // CAP (1 MB)
    float* pm      = logits + CAP;               // G1 (16B-aligned)
    float* ps      = pm + G1;                    // G1
    float* partial = ps + G1;                    // G1*NF (4 MB)
    float* part2   = partial + (size_t)G1 * NF;  // GR*NF (128 KB)

    k_logits     <<<G1, 256, 0, stream>>>(q, keys, logits, pm, ps);
    k_wsum_sparse<<<G1, 256, 0, stream>>>(vals, logits, pm, partial);
    k_red        <<<GR, 256, 0, stream>>>(pm, partial, part2);
    k_final      <<<2,  256, 0, stream>>>(pm, ps, part2, out);
}